// Round 2
// baseline (160.338 us; speedup 1.0000x reference)
//
#include <hip/hip_runtime.h>

#define NCLASS 16
#define D 128
#define EPSF 1e-6f
#define MF 10.0f

// ws layout (floats): S[NCLASS*D] | Q[NCLASS] | CNT[NCLASS] | sumLoss | sumValid
#define WS_S   0
#define WS_Q   (NCLASS * D)       // 2048
#define WS_CNT (WS_Q + NCLASS)    // 2064
#define WS_SUM (WS_CNT + NCLASS)  // 2080
#define WS_FLOATS (WS_SUM + 2)    // 2082

// Kernel 1: per-class aggregation, latency-optimized.
// 256 blocks x 256 threads. Per block-iteration: 8 rows x 32 float4-lanes.
// All global addresses are independent of the label -> loads pipeline fully.
// Class sums accumulate in REGISTERS (16-class unrolled predication) -> no
// LDS dependence chain in the hot loop. Fan-in: LDS atomics, then one global
// atomicAdd per (block, address).
__global__ void __launch_bounds__(256)
agg_kernel(const float* __restrict__ F, const int* __restrict__ L,
           float* __restrict__ ws, int n) {
    __shared__ float Ssh[NCLASS * D];
    __shared__ float qsh[NCLASS];
    __shared__ float csh[NCLASS];
    const int tid = threadIdx.x;
    const int sub = tid & 31;   // float4 index within a row (32*4 = 128 cols)
    const int rg  = tid >> 5;   // row 0..7 within the 8-row chunk
    const float isLeader = (sub == 0) ? 1.f : 0.f;

    for (int i = tid; i < NCLASS * D; i += 256) Ssh[i] = 0.f;
    if (tid < NCLASS) { qsh[tid] = 0.f; csh[tid] = 0.f; }
    __syncthreads();

    float s0[NCLASS], s1[NCLASS], s2[NCLASS], s3[NCLASS], qa[NCLASS], ca[NCLASS];
    #pragma unroll
    for (int c = 0; c < NCLASS; ++c) { s0[c]=s1[c]=s2[c]=s3[c]=qa[c]=ca[c]=0.f; }

    const float4* __restrict__ F4 = (const float4*)F;
    for (int r0 = blockIdx.x * 8; r0 < n; r0 += gridDim.x * 8) {
        const int r = r0 + rg;
        if (r >= n) break;
        const int lc = L[r];
        const float4 v = F4[(size_t)r * 32 + sub];
        const float vv = v.x*v.x + v.y*v.y + v.z*v.z + v.w*v.w;
        #pragma unroll
        for (int c = 0; c < NCLASS; ++c) {
            const bool m = (lc == c);
            s0[c] += m ? v.x : 0.f;
            s1[c] += m ? v.y : 0.f;
            s2[c] += m ? v.z : 0.f;
            s3[c] += m ? v.w : 0.f;
            qa[c] += m ? vv  : 0.f;
            ca[c] += m ? isLeader : 0.f;
        }
    }
    #pragma unroll
    for (int c = 0; c < NCLASS; ++c) {
        atomicAdd(&Ssh[c * D + sub * 4 + 0], s0[c]);
        atomicAdd(&Ssh[c * D + sub * 4 + 1], s1[c]);
        atomicAdd(&Ssh[c * D + sub * 4 + 2], s2[c]);
        atomicAdd(&Ssh[c * D + sub * 4 + 3], s3[c]);
        atomicAdd(&qsh[c], qa[c]);
        atomicAdd(&csh[c], ca[c]);
    }
    __syncthreads();
    for (int i = tid; i < NCLASS * D; i += 256) atomicAdd(&ws[WS_S + i], Ssh[i]);
    if (tid < NCLASS) {
        atomicAdd(&ws[WS_Q + tid], qsh[tid]);
        atomicAdd(&ws[WS_CNT + tid], csh[tid]);
    }
}

// Kernel 2: one wave per row-group; 1024 waves, 8 rows per wave.
// float2 per lane covers D=128; three wave shuffle-reductions per row.
__global__ void __launch_bounds__(256)
loss_kernel(const float* __restrict__ F, const int* __restrict__ L,
            float* __restrict__ ws, int n) {
    __shared__ float S_lds[NCLASS * D];
    __shared__ float Stot[D];
    __shared__ float Q_lds[NCLASS];
    __shared__ float cnt_lds[NCLASS];
    __shared__ float Qtot_s;

    for (int i = threadIdx.x; i < NCLASS * D; i += blockDim.x)
        S_lds[i] = ws[WS_S + i];
    if (threadIdx.x < NCLASS) {
        Q_lds[threadIdx.x] = ws[WS_Q + threadIdx.x];
        cnt_lds[threadIdx.x] = ws[WS_CNT + threadIdx.x];
    }
    __syncthreads();
    if (threadIdx.x < D) {
        float s = 0.f;
        #pragma unroll
        for (int c = 0; c < NCLASS; ++c) s += S_lds[c * D + threadIdx.x];
        Stot[threadIdx.x] = s;
    }
    if (threadIdx.x == 0) {
        float q = 0.f;
        #pragma unroll
        for (int c = 0; c < NCLASS; ++c) q += Q_lds[c];
        Qtot_s = q;
    }
    __syncthreads();

    const int lane = threadIdx.x & 63;
    const int wave = threadIdx.x >> 6;
    const int gw = blockIdx.x * (blockDim.x >> 6) + wave;
    const int nw = gridDim.x * (blockDim.x >> 6);
    const float nf = (float)n;

    float accL = 0.f, accV = 0.f;
    for (int r = gw; r < n; r += nw) {
        const int c = L[r];  // wave-uniform
        const float2 v = ((const float2*)(F + (size_t)r * D))[lane];
        const float a0 = S_lds[c * D + 2 * lane];
        const float a1 = S_lds[c * D + 2 * lane + 1];
        const float t0 = Stot[2 * lane];
        const float t1 = Stot[2 * lane + 1];
        float sq    = v.x * v.x + v.y * v.y;
        float dsame = v.x * a0 + v.y * a1;
        float dtot  = v.x * t0 + v.y * t1;
        #pragma unroll
        for (int off = 32; off; off >>= 1) {
            sq    += __shfl_xor(sq, off, 64);
            dsame += __shfl_xor(dsame, off, 64);
            dtot  += __shfl_xor(dtot, off, 64);
        }
        if (lane == 0) {
            const float cntc   = cnt_lds[c];
            const float counts = cntc - 1.f;
            const float same_sum = counts * sq + sq + Q_lds[c] - 2.f * dsame;
            const float diff_sum = (nf - cntc) * sq + (Qtot_s - Q_lds[c])
                                   - 2.f * (dtot - dsame);
            const float loss = same_sum / (counts + EPSF)
                             - diff_sum / (nf - cntc + EPSF) + MF;
            const float valid = counts > 0.5f ? 1.f : 0.f;
            accL += (loss > 0.f ? loss : 0.f) * valid;
            accV += valid;
        }
    }
    if (lane == 0) {
        atomicAdd(&ws[WS_SUM], accL);
        atomicAdd(&ws[WS_SUM + 1], accV);
    }
}

__global__ void final_kernel(const float* __restrict__ ws, float* __restrict__ out) {
    out[0] = ws[WS_SUM] / fmaxf(ws[WS_SUM + 1], 1.f);
}

extern "C" void kernel_launch(void* const* d_in, const int* in_sizes, int n_in,
                              void* d_out, int out_size, void* d_ws, size_t ws_size,
                              hipStream_t stream) {
    const float* F = (const float*)d_in[0];
    const int* L = (const int*)d_in[1];
    float* out = (float*)d_out;
    float* ws = (float*)d_ws;
    const int n = in_sizes[1];  // 8192 rows; in_sizes[0]/n == 128 == D

    hipMemsetAsync(d_ws, 0, WS_FLOATS * sizeof(float), stream);
    agg_kernel<<<256, 256, 0, stream>>>(F, L, ws, n);
    loss_kernel<<<256, 256, 0, stream>>>(F, L, ws, n);
    final_kernel<<<1, 1, 0, stream>>>(ws, out);
}

// Round 3
// 84.575 us; speedup vs baseline: 1.8958x; 1.8958x over previous
//
#include <hip/hip_runtime.h>

#define NCLASS 16
#define D 128
#define EPSF 1e-6f
#define MF 10.0f

// ws layout (floats): S[2048] | Q[16] | CNT[16] | sumLoss,sumValid | done
#define WS_S   0
#define WS_Q   (NCLASS * D)       // 2048
#define WS_CNT (WS_Q + NCLASS)    // 2064
#define WS_SUM (WS_CNT + NCLASS)  // 2080 (sumLoss), 2081 (sumValid)
#define WS_DONE 2082              // uint completion counter
#define WS_FLOATS 2084

#define AGG_BLOCKS 64
#define AGG_THREADS 512
#define AGG_WAVES (AGG_THREADS / 64)

// Per-class aggregation. NO LDS atomics (round-2 lesson: same-address DS RMW
// serializes 64-way, ~58us). Registers -> conflict-free LDS stores ->
// block tree-reduce -> one global atomicAdd per (block, address).
__global__ void __launch_bounds__(AGG_THREADS)
agg_kernel(const float* __restrict__ F, const int* __restrict__ L,
           float* __restrict__ ws, int n) {
    __shared__ float Ssh[AGG_WAVES][NCLASS][D];   // 64 KB
    __shared__ float qsh[AGG_WAVES][NCLASS];
    __shared__ float csh[AGG_WAVES][NCLASS];
    const int tid  = threadIdx.x;
    const int lane = tid & 63;
    const int wv   = tid >> 6;
    const int gw   = blockIdx.x * AGG_WAVES + wv;
    const int nwv  = AGG_BLOCKS * AGG_WAVES;      // 512 waves

    float ax[NCLASS], ay[NCLASS], qa[NCLASS], ca[NCLASS];
    #pragma unroll
    for (int c = 0; c < NCLASS; ++c) { ax[c] = ay[c] = qa[c] = ca[c] = 0.f; }

    const float2* __restrict__ F2 = (const float2*)F;
    #pragma unroll 4
    for (int r = gw; r < n; r += nwv) {           // 16 iterations
        const int lc = L[r];                      // wave-uniform broadcast
        const float2 v = F2[(size_t)r * 64 + lane];
        const float sq = fmaf(v.x, v.x, v.y * v.y);
        #pragma unroll
        for (int c = 0; c < NCLASS; ++c) {
            const float sel = (lc == c) ? 1.f : 0.f;
            ax[c] = fmaf(sel, v.x, ax[c]);
            ay[c] = fmaf(sel, v.y, ay[c]);
            qa[c] = fmaf(sel, sq, qa[c]);
            ca[c] += sel;                         // wave-uniform result
        }
    }
    // wave-reduce qa via butterfly (ca needs none: identical in every lane)
    #pragma unroll
    for (int c = 0; c < NCLASS; ++c) {
        float q = qa[c];
        #pragma unroll
        for (int off = 32; off; off >>= 1) q += __shfl_xor(q, off, 64);
        qa[c] = q;
    }
    // conflict-free stores: cell (wv,c,2*lane..2*lane+1) owned by this lane
    #pragma unroll
    for (int c = 0; c < NCLASS; ++c) {
        ((float2*)&Ssh[wv][c][0])[lane] = make_float2(ax[c], ay[c]);
    }
    if (lane == 0) {
        #pragma unroll
        for (int c = 0; c < NCLASS; ++c) { qsh[wv][c] = qa[c]; csh[wv][c] = ca[c]; }
    }
    __syncthreads();
    // block-reduce across waves, then one global atomic per address
    const float* Sflat = &Ssh[0][0][0];
    for (int p = tid; p < NCLASS * D; p += AGG_THREADS) {  // 4 iterations
        float s = 0.f;
        #pragma unroll
        for (int w = 0; w < AGG_WAVES; ++w) s += Sflat[w * NCLASS * D + p];
        atomicAdd(&ws[WS_S + p], s);
    }
    if (tid < NCLASS) {
        float q = 0.f, cc = 0.f;
        #pragma unroll
        for (int w = 0; w < AGG_WAVES; ++w) { q += qsh[w][tid]; cc += csh[w][tid]; }
        atomicAdd(&ws[WS_Q + tid], q);
        atomicAdd(&ws[WS_CNT + tid], cc);
    }
}

#define LOSS_BLOCKS 256
#define LOSS_THREADS 256
#define LOSS_WAVES (LOSS_THREADS / 64)

// One wave per row (8 rows/wave). Block-reduces loss/valid -> 2 global atomics
// per block. Final division fused via done-counter (last block writes out).
__global__ void __launch_bounds__(LOSS_THREADS)
loss_kernel(const float* __restrict__ F, const int* __restrict__ L,
            float* __restrict__ ws, float* __restrict__ out, int n) {
    __shared__ float S_lds[NCLASS * D];
    __shared__ float Stot[D];
    __shared__ float Q_lds[NCLASS];
    __shared__ float cnt_lds[NCLASS];
    __shared__ float Qtot_s;
    __shared__ float redL[LOSS_WAVES], redV[LOSS_WAVES];

    const int tid = threadIdx.x;
    const float4* ws4 = (const float4*)(ws + WS_S);
    float4* S4 = (float4*)S_lds;
    for (int i = tid; i < NCLASS * D / 4; i += LOSS_THREADS) S4[i] = ws4[i];
    if (tid < NCLASS) {
        Q_lds[tid] = ws[WS_Q + tid];
        cnt_lds[tid] = ws[WS_CNT + tid];
    }
    __syncthreads();
    if (tid < D) {
        float s = 0.f;
        #pragma unroll
        for (int c = 0; c < NCLASS; ++c) s += S_lds[c * D + tid];
        Stot[tid] = s;
    }
    if (tid == 0) {
        float q = 0.f;
        #pragma unroll
        for (int c = 0; c < NCLASS; ++c) q += Q_lds[c];
        Qtot_s = q;
    }
    __syncthreads();

    const int lane = tid & 63;
    const int wv = tid >> 6;
    const int gw = blockIdx.x * LOSS_WAVES + wv;
    const int nw = LOSS_BLOCKS * LOSS_WAVES;   // 1024 waves
    const float nf = (float)n;
    const float2* __restrict__ F2 = (const float2*)F;
    const float2* __restrict__ S2 = (const float2*)S_lds;
    const float2* __restrict__ T2 = (const float2*)Stot;

    float accL = 0.f, accV = 0.f;
    #pragma unroll 2
    for (int r = gw; r < n; r += nw) {          // 8 iterations
        const int c = L[r];                      // wave-uniform
        const float2 v = F2[(size_t)r * 64 + lane];
        const float2 a = S2[c * 64 + lane];
        const float2 t = T2[lane];
        float sq    = fmaf(v.x, v.x, v.y * v.y);
        float dsame = fmaf(v.x, a.x, v.y * a.y);
        float dtot  = fmaf(v.x, t.x, v.y * t.y);
        #pragma unroll
        for (int off = 32; off; off >>= 1) {
            sq    += __shfl_xor(sq, off, 64);
            dsame += __shfl_xor(dsame, off, 64);
            dtot  += __shfl_xor(dtot, off, 64);
        }
        const float cntc   = cnt_lds[c];
        const float counts = cntc - 1.f;
        const float same_sum = counts * sq + sq + Q_lds[c] - 2.f * dsame;
        const float diff_sum = (nf - cntc) * sq + (Qtot_s - Q_lds[c])
                               - 2.f * (dtot - dsame);
        const float loss = same_sum / (counts + EPSF)
                         - diff_sum / (nf - cntc + EPSF) + MF;
        const float valid = counts > 0.5f ? 1.f : 0.f;
        accL += (loss > 0.f ? loss : 0.f) * valid;
        accV += valid;
    }
    if (lane == 0) { redL[wv] = accL; redV[wv] = accV; }
    __syncthreads();
    if (tid == 0) {
        float sL = 0.f, sV = 0.f;
        #pragma unroll
        for (int w = 0; w < LOSS_WAVES; ++w) { sL += redL[w]; sV += redV[w]; }
        atomicAdd(&ws[WS_SUM], sL);
        atomicAdd(&ws[WS_SUM + 1], sV);
        __threadfence();
        unsigned done = __hip_atomic_fetch_add((unsigned*)&ws[WS_DONE], 1u,
                                               __ATOMIC_ACQ_REL,
                                               __HIP_MEMORY_SCOPE_AGENT);
        if (done == (unsigned)(gridDim.x - 1)) {   // last block: final divide
            float sl = __hip_atomic_load(&ws[WS_SUM], __ATOMIC_RELAXED,
                                         __HIP_MEMORY_SCOPE_AGENT);
            float sv = __hip_atomic_load(&ws[WS_SUM + 1], __ATOMIC_RELAXED,
                                         __HIP_MEMORY_SCOPE_AGENT);
            out[0] = sl / fmaxf(sv, 1.f);
        }
    }
}

extern "C" void kernel_launch(void* const* d_in, const int* in_sizes, int n_in,
                              void* d_out, int out_size, void* d_ws, size_t ws_size,
                              hipStream_t stream) {
    const float* F = (const float*)d_in[0];
    const int* L = (const int*)d_in[1];
    float* out = (float*)d_out;
    float* ws = (float*)d_ws;
    const int n = in_sizes[1];  // 8192 rows; D = in_sizes[0]/n = 128

    hipMemsetAsync(d_ws, 0, WS_FLOATS * sizeof(float), stream);
    agg_kernel<<<AGG_BLOCKS, AGG_THREADS, 0, stream>>>(F, L, ws, n);
    loss_kernel<<<LOSS_BLOCKS, LOSS_THREADS, 0, stream>>>(F, L, ws, out, n);
}